// Round 5
// baseline (448.794 us; speedup 1.0000x reference)
//
#include <hip/hip_runtime.h>
#include <stdint.h>

#define BATCH 8192
#define H1 28
#define W1 28
#define C1 16
#define P1 14
#define C2 32
#define P2 7

#define NPIX1  (BATCH*H1*W1)    // 6,422,528
#define NPOOL1 (BATCH*P1*P1)    // 1,605,632
#define NPOOL2 (BATCH*P2*P2)    // 401,408

#define C1S_BLOCKS 3136         // conv1 stats: 128 pos * 4 iters per block
#define C1S_ITERS  4
#define A1_BLOCKS  6272         // NPOOL1/256
#define C2F_BLOCKS 6272         // NPOOL2*4/256 (quarter channel split)

typedef float f32x2 __attribute__((ext_vector_type(2)));

// ---------------------------------------------------------------------------
// Weight prep.
//  w1s : 25-bit sign masks [16]
//  w2b : u16 channel masks [32][25] (bit ci = w>=0)
//  w2p : packed tap-pairs  [32][13]
//  w2k : border-correction K table [25 classes][32], K = 16*nv + 2*C_invalid
//  fcp : packed sign bytes [10][392]
//  selb: {g1<0 bits, g2<0 bits}
// ---------------------------------------------------------------------------
__global__ __launch_bounds__(256) void k_prep(const float* __restrict__ w1,
                                              const float* __restrict__ w2,
                                              const float* __restrict__ fcw,
                                              const float* __restrict__ g1,
                                              const float* __restrict__ g2,
                                              unsigned* __restrict__ w1s,
                                              unsigned short* __restrict__ w2b,
                                              unsigned* __restrict__ w2p,
                                              unsigned short* __restrict__ w2k,
                                              unsigned* __restrict__ fcp,
                                              unsigned* __restrict__ selb) {
    for (int c = threadIdx.x; c < 16; c += blockDim.x) {
        unsigned sb = 0;
        for (int i = 0; i < 25; ++i)
            if (w1[c*25 + i] < 0.f) sb |= 1u << i;
        w1s[c] = sb;
    }
    for (int i = threadIdx.x; i < 800; i += blockDim.x) {
        int co = i / 25, kk = i % 25;
        unsigned m = 0;
        for (int ci = 0; ci < 16; ++ci)
            if (w2[co*400 + ci*25 + kk] >= 0.f) m |= 1u << ci;
        w2b[i] = (unsigned short)m;
    }
    for (int i = threadIdx.x; i < 32*13; i += blockDim.x) {
        int co = i / 13, j = i % 13;
        int k1, k2;
        if (j < 10)      { k1 = (j/2)*5 + (j&1)*2; k2 = k1 + 1; }
        else if (j == 10){ k1 = 4;  k2 = 9;  }
        else if (j == 11){ k1 = 14; k2 = 19; }
        else             { k1 = 24; k2 = -1; }
        unsigned lo = 0, hi = 0;
        for (int ci = 0; ci < 16; ++ci) {
            if (w2[co*400 + ci*25 + k1] >= 0.f) lo |= 1u << ci;
            if (k2 >= 0 && w2[co*400 + ci*25 + k2] >= 0.f) hi |= 1u << ci;
        }
        w2p[i] = lo | (hi << 16);
    }
    for (int i = threadIdx.x; i < 3920; i += blockDim.x) {
        int j = i / 392, g = i % 392;
        unsigned v = 0;
        for (int by = 0; by < 4; ++by) {
            int k = g*4 + by;
            unsigned char s = (fcw[j*1568 + k] >= 0.f) ? 0x01 : 0xFF;
            v |= ((unsigned)s) << (8*by);
        }
        fcp[i] = v;
    }
    if (threadIdx.x == 0) {
        unsigned s1 = 0, s2 = 0;
        for (int c = 0; c < 16; ++c) if (g1[c] < 0.f) s1 |= 1u << c;
        for (int c = 0; c < 32; ++c) if (g2[c] < 0.f) s2 |= 1u << c;
        selb[0] = s1; selb[1] = s2;
    }
    __syncthreads();   // w2b ready -> build K table
    {
        const int lo5[5] = {2,1,0,0,0};
        const int hi5[5] = {4,4,4,3,2};
        for (int i = threadIdx.x; i < 800; i += blockDim.x) {
            int cls = i >> 5, co = i & 31;
            int rc = cls / 5, cc = cls % 5;
            int rlo = lo5[rc], rhi = hi5[rc], clo = lo5[cc], chi = hi5[cc];
            int C = 0;
            for (int ky = 0; ky < 5; ++ky)
                for (int kx = 0; kx < 5; ++kx)
                    if (ky < rlo || ky > rhi || kx < clo || kx > chi)
                        C += __popc((unsigned)w2b[co*25 + ky*5 + kx]);
            int nv = (rhi - rlo + 1) * (chi - clo + 1);
            w2k[i] = (unsigned short)(16*nv + 2*C);
        }
    }
}

// ---------------------------------------------------------------------------
// conv1 stats: channel-split-2 (8 ch/thread), 4 positions/thread, f64 stats
// in registers, one parity-preserving butterfly per thread.
// Exact f32 chains (tap order 0..24, ±1 sign-flip pk adds == fmaf).
// NOTE: sign masks loaded per-thread (plain loads) — c0 is lane-dependent,
// so readfirstlane here would broadcast the WRONG mask (round-4 bug).
// ---------------------------------------------------------------------------
__global__ __launch_bounds__(256) void k_conv1_stats2(const float* __restrict__ x,
                                                      const unsigned* __restrict__ w1s,
                                                      const float* __restrict__ b1,
                                                      double* __restrict__ partial1) {
    int half = threadIdx.x & 1;
    int c0 = half << 3;
    unsigned sbv[8];
    float bv[8];
#pragma unroll
    for (int cl = 0; cl < 8; ++cl) {
        sbv[cl] = w1s[c0 + cl];      // per-lane load, NOT readfirstlane
        bv[cl]  = b1[c0 + cl];
    }
    double s[8], q[8];
#pragma unroll
    for (int i = 0; i < 8; ++i) { s[i] = 0.0; q[i] = 0.0; }

#pragma unroll 1
    for (int it = 0; it < C1S_ITERS; ++it) {
        int p = blockIdx.x*(128*C1S_ITERS) + it*128 + (threadIdx.x >> 1);
        int b = p / (P1*P1);
        int r = p % (P1*P1);
        int py = r / P1, px = r % P1;
        const float* xb = x + (size_t)b * (H1*W1);

        float xd[36];
#pragma unroll
        for (int dy = 0; dy < 6; ++dy) {
            int iy = 2*py + dy - 2;
#pragma unroll
            for (int dx = 0; dx < 6; ++dx) {
                int ix = 2*px + dx - 2;
                xd[dy*6 + dx] = (iy >= 0 && iy < H1 && ix >= 0 && ix < W1)
                              ? xb[iy*W1 + ix] : 0.f;
            }
        }

#pragma unroll
        for (int cl = 0; cl < 8; ++cl) {
            unsigned sb = sbv[cl];
            f32x2 y01 = {0.f, 0.f}, y23 = {0.f, 0.f};
#pragma unroll
            for (int ky = 0; ky < 5; ++ky) {
#pragma unroll
                for (int kx = 0; kx < 5; ++kx) {
                    float m = __uint_as_float(0x3F800000u ^
                                (((sb >> (ky*5 + kx)) & 1u) << 31));
                    f32x2 x01 = { xd[ ky   *6 + kx], xd[ ky   *6 + kx + 1] };
                    f32x2 x23 = { xd[(ky+1)*6 + kx], xd[(ky+1)*6 + kx + 1] };
                    y01 = x01 * m + y01;
                    y23 = x23 * m + y23;
                }
            }
            float bbc = bv[cl];
            double d0 = (double)(y01.x + bbc), d1 = (double)(y01.y + bbc);
            double d2 = (double)(y23.x + bbc), d3 = (double)(y23.y + bbc);
            s[cl] += (d0 + d1) + (d2 + d3);
            q[cl] += (d0*d0 + d1*d1) + (d2*d2 + d3*d3);
        }
    }

    __shared__ double lsum[4][16], lsq[4][16];
    int wave = threadIdx.x >> 6, lane = threadIdx.x & 63;
#pragma unroll
    for (int cl = 0; cl < 8; ++cl) {
        double ss = s[cl], qq = q[cl];
#pragma unroll
        for (int off = 32; off >= 2; off >>= 1) {   // parity-preserving
            ss += __shfl_down(ss, off);
            qq += __shfl_down(qq, off);
        }
        if (lane <= 1) { lsum[wave][lane*8 + cl] = ss; lsq[wave][lane*8 + cl] = qq; }
    }
    __syncthreads();
    if (threadIdx.x < 16) {
        int c = threadIdx.x;
        partial1[(size_t)blockIdx.x*32 + c] =
            lsum[0][c] + lsum[1][c] + lsum[2][c] + lsum[3][c];
    } else if (threadIdx.x < 32) {
        int c = threadIdx.x - 16;
        partial1[(size_t)blockIdx.x*32 + 16 + c] =
            lsq[0][c] + lsq[1][c] + lsq[2][c] + lsq[3][c];
    }
}

// finalize1: reduce partials, per-channel threshold + mode
__global__ __launch_bounds__(256) void k_finalize1(const double* __restrict__ part,
                                                   int nblk,
                                                   const float* __restrict__ g,
                                                   const float* __restrict__ be,
                                                   double* __restrict__ thr,
                                                   int* __restrict__ mode) {
    int c = blockIdx.x;
    double s = 0, q = 0;
    for (int i = threadIdx.x; i < nblk; i += 256) {
        s += part[(size_t)i*32 + c];
        q += part[(size_t)i*32 + 16 + c];
    }
    __shared__ double ls[256], lq[256];
    ls[threadIdx.x] = s; lq[threadIdx.x] = q;
    __syncthreads();
    for (int st = 128; st > 0; st >>= 1) {
        if (threadIdx.x < st) {
            ls[threadIdx.x] += ls[threadIdx.x + st];
            lq[threadIdx.x] += lq[threadIdx.x + st];
        }
        __syncthreads();
    }
    if (threadIdx.x == 0) {
        double N = (double)NPIX1;
        double m = ls[0] / N;
        double var = lq[0] / N - m*m;
        double gamma = (double)g[c], beta = (double)be[c];
        double sc = gamma / sqrt(var + 1e-5);
        int md; double tt = 0.0;
        if (sc > 0)      { md = 0; tt = m - beta / sc; }
        else if (sc < 0) { md = 1; tt = m - beta / sc; }
        else             { md = (beta >= 0) ? 2 : 3; }
        thr[c] = tt; mode[c] = md;
    }
}

// ---------------------------------------------------------------------------
// a1: recompute conv1 (identical chains), pool, compare thresholds -> bitmask.
// (readfirstlane is safe here: c loop is wave-uniform.)
// ---------------------------------------------------------------------------
__global__ __launch_bounds__(256) void k_a1_fast(const float* __restrict__ x,
                                                 const unsigned* __restrict__ w1s,
                                                 const float* __restrict__ b1,
                                                 const double* __restrict__ thr,
                                                 const int* __restrict__ mode,
                                                 unsigned short* __restrict__ a1b) {
    int t = blockIdx.x*256 + threadIdx.x;
    int b = t / (P1*P1);
    int r = t % (P1*P1);
    int py = r / P1, px = r % P1;
    const float* xb = x + (size_t)b * (H1*W1);

    float xd[36];
#pragma unroll
    for (int dy = 0; dy < 6; ++dy) {
        int iy = 2*py + dy - 2;
#pragma unroll
        for (int dx = 0; dx < 6; ++dx) {
            int ix = 2*px + dx - 2;
            xd[dy*6 + dx] = (iy >= 0 && iy < H1 && ix >= 0 && ix < W1)
                          ? xb[iy*W1 + ix] : 0.f;
        }
    }

    unsigned bits = 0;
#pragma unroll 1
    for (int c = 0; c < 16; ++c) {
        unsigned sb = __builtin_amdgcn_readfirstlane(w1s[c]);
        f32x2 y01 = {0.f, 0.f}, y23 = {0.f, 0.f};
#pragma unroll
        for (int ky = 0; ky < 5; ++ky) {
#pragma unroll
            for (int kx = 0; kx < 5; ++kx) {
                float m = __uint_as_float(0x3F800000u ^
                            (((sb >> (ky*5 + kx)) & 1u) << 31));
                f32x2 x01 = { xd[ ky   *6 + kx], xd[ ky   *6 + kx + 1] };
                f32x2 x23 = { xd[(ky+1)*6 + kx], xd[(ky+1)*6 + kx + 1] };
                y01 = x01 * m + y01;
                y23 = x23 * m + y23;
            }
        }
        float bbc = b1[c];
        float y0 = y01.x + bbc, y1 = y01.y + bbc;
        float y2 = y23.x + bbc, y3 = y23.y + bbc;
        float mx = fmaxf(fmaxf(y0, y1), fmaxf(y2, y3));
        float mn = fminf(fminf(y0, y1), fminf(y2, y3));
        int md = mode[c]; double tt = thr[c];
        bool plus = (md == 0) ? ((double)mx >= tt)
                  : (md == 1) ? ((double)mn <= tt)
                  : (md == 2);
        bits |= (plus ? 1u : 0u) << c;
    }
    a1b[t] = (unsigned short)bits;
}

// ---------------------------------------------------------------------------
// conv2 fused: LDS-staged zero-padded images + K-corrected XNOR-popcount.
// Block: 64 pooled positions x 4 channel-quarters. Stages <=3 images.
// y = K[class][co] - 2*popc_full  (exact integers).
// ---------------------------------------------------------------------------
__global__ __launch_bounds__(256) void k_conv2_fused(const unsigned short* __restrict__ a1b,
                                                     const unsigned* __restrict__ w2p,
                                                     const unsigned short* __restrict__ w2k,
                                                     const unsigned* __restrict__ selb,
                                                     short* __restrict__ ext2,
                                                     int* __restrict__ partial2) {
    __shared__ unsigned short raw[3*18*18];
    __shared__ unsigned sw[32*13];
    __shared__ unsigned short kt[25*32];
    __shared__ int lsum[4][32], lsq[4][32];

    const int B0 = blockIdx.x * 64;
    const int i0 = B0 / 49;
    const int ilast = (B0 + 63) / 49;
    const int icnt = ilast - i0 + 1;       // 2 or 3

    for (int i = threadIdx.x; i < 416; i += 256) sw[i] = w2p[i];
    for (int i = threadIdx.x; i < 800; i += 256) kt[i] = w2k[i];
    {   // zero padded tiles
        unsigned* rz = (unsigned*)raw;
        int n32 = icnt * 162;
        for (int i = threadIdx.x; i < n32; i += 256) rz[i] = 0u;
    }
    __syncthreads();
    {   // fill valid interior
        int n = icnt * 196;
        for (int e = threadIdx.x; e < n; e += 256) {
            int img = e / 196, lin = e % 196;
            unsigned short v = a1b[(size_t)(i0 + img)*196 + lin];
            int py = lin / 14, px = lin % 14;
            raw[(img*18 + py + 2)*18 + px + 2] = v;
        }
    }
    __syncthreads();

    const int quarter = threadIdx.x & 3;
    const int c0 = quarter << 3;
    const int t = B0 + (threadIdx.x >> 2);
    const int img = t / 49 - i0;
    const int r = t % 49;
    const int qy = r / 7, qx = r % 7;
    const unsigned selbs = __builtin_amdgcn_readfirstlane(selb[1]);

    unsigned am[36];
#pragma unroll
    for (int wy = 0; wy < 6; ++wy)
#pragma unroll
        for (int wx = 0; wx < 6; ++wx)
            am[wy*6 + wx] = (unsigned)raw[(img*18 + 2*qy + wy)*18 + 2*qx + wx];

    int s[8], q[8], mx[8], mn[8];
#pragma unroll
    for (int i = 0; i < 8; ++i) { s[i]=0; q[i]=0; mx[i]=-1000000; mn[i]=1000000; }

#pragma unroll
    for (int sp = 0; sp < 4; ++sp) {
        const int sy = sp >> 1, sx = sp & 1;
        const int oy = 2*qy + sy, ox = 2*qx + sx;
        const int rcls = (oy < 2) ? oy : ((oy > 11) ? oy - 9 : 2);
        const int ccls = (ox < 2) ? ox : ((ox > 11) ? ox - 9 : 2);
        const int kbase = (rcls*5 + ccls) * 32 + c0;

        unsigned ap[13];
#pragma unroll
        for (int ky = 0; ky < 5; ++ky) {
            ap[ky*2+0] = am[(sy+ky)*6 + sx+0] | (am[(sy+ky)*6 + sx+1] << 16);
            ap[ky*2+1] = am[(sy+ky)*6 + sx+2] | (am[(sy+ky)*6 + sx+3] << 16);
        }
        ap[10] = am[(sy+0)*6 + sx+4] | (am[(sy+1)*6 + sx+4] << 16);
        ap[11] = am[(sy+2)*6 + sx+4] | (am[(sy+3)*6 + sx+4] << 16);
        ap[12] = am[(sy+4)*6 + sx+4];

#pragma unroll
        for (int cl = 0; cl < 8; ++cl) {
            const unsigned* wr = sw + (c0 + cl)*13;
            int p = 0;
#pragma unroll
            for (int j = 0; j < 13; ++j)
                p += __popc(ap[j] ^ wr[j]);
            int y = (int)kt[kbase + cl] - 2*p;
            s[cl] += y; q[cl] += y*y;
            mx[cl] = (y > mx[cl]) ? y : mx[cl];
            mn[cl] = (y < mn[cl]) ? y : mn[cl];
        }
    }

#pragma unroll
    for (int cl = 0; cl < 8; ++cl) {
        int co = c0 + cl;
        int sel = (selbs >> co) & 1;
        ext2[(size_t)co*NPOOL2 + t] = (short)(sel ? mn[cl] : mx[cl]);
    }

    int wave = threadIdx.x >> 6, lane = threadIdx.x & 63;
#pragma unroll
    for (int cl = 0; cl < 8; ++cl) {
        int ss = s[cl], qq = q[cl];
#pragma unroll
        for (int off = 32; off >= 4; off >>= 1) {   // quarter-preserving
            ss += __shfl_down(ss, off);
            qq += __shfl_down(qq, off);
        }
        if (lane < 4) {
            lsum[wave][lane*8 + cl] = ss;
            lsq[wave][lane*8 + cl]  = qq;
        }
    }
    __syncthreads();
    if (threadIdx.x < 32) {
        int co = threadIdx.x;
        partial2[(size_t)blockIdx.x*64 + co] =
            lsum[0][co] + lsum[1][co] + lsum[2][co] + lsum[3][co];
    } else if (threadIdx.x < 64) {
        int co = threadIdx.x - 32;
        partial2[(size_t)blockIdx.x*64 + 32 + co] =
            lsq[0][co] + lsq[1][co] + lsq[2][co] + lsq[3][co];
    }
}

// finalize2 (int partials); thr on (y + bias) scale
__global__ __launch_bounds__(256) void k_finalize2i(const int* __restrict__ part,
                                                    int nblk,
                                                    const float* __restrict__ b2,
                                                    const float* __restrict__ g,
                                                    const float* __restrict__ be,
                                                    double* __restrict__ thr,
                                                    int* __restrict__ mode) {
    int c = blockIdx.x;
    long long s = 0, q = 0;
    for (int i = threadIdx.x; i < nblk; i += 256) {
        s += (long long)part[(size_t)i*64 + c];
        q += (long long)part[(size_t)i*64 + 32 + c];
    }
    __shared__ long long ls[256], lq[256];
    ls[threadIdx.x] = s; lq[threadIdx.x] = q;
    __syncthreads();
    for (int st = 128; st > 0; st >>= 1) {
        if (threadIdx.x < st) {
            ls[threadIdx.x] += ls[threadIdx.x + st];
            lq[threadIdx.x] += lq[threadIdx.x + st];
        }
        __syncthreads();
    }
    if (threadIdx.x == 0) {
        double N = (double)(BATCH * P1 * P1);
        double my = (double)ls[0] / N;
        double var = (double)lq[0] / N - my*my;   // bias-shift invariant
        double m = my + (double)b2[c];
        double gamma = (double)g[c], beta = (double)be[c];
        double sc = gamma / sqrt(var + 1e-5);
        int md; double tt = 0.0;
        if (sc > 0)      { md = 0; tt = m - beta / sc; }
        else if (sc < 0) { md = 1; tt = m - beta / sc; }
        else             { md = (beta >= 0) ? 2 : 3; }
        thr[c] = tt; mode[c] = md;
    }
}

// stage-2 signs; emulate fl32(y + b2) exactly before f64 compare
__global__ __launch_bounds__(256) void k_sign2(const short* __restrict__ ext2,
                                               const float* __restrict__ b2,
                                               const double* __restrict__ thr,
                                               const int* __restrict__ mode,
                                               char* __restrict__ a2) {
    int t = blockIdx.x*256 + threadIdx.x;
    int b = t / (P2*P2);
    int r = t % (P2*P2);
#pragma unroll 1
    for (int co = 0; co < 32; ++co) {
        short v = ext2[(size_t)co*NPOOL2 + t];
        float yf = (float)v + b2[co];
        int md = mode[co]; double tt = thr[co];
        bool plus = (md == 0) ? ((double)yf >= tt)
                  : (md == 1) ? ((double)yf <= tt)
                  : (md == 2);
        a2[(size_t)b*1568 + co*49 + r] = plus ? (char)1 : (char)-1;
    }
}

// FC: popcount dot over ±1 bytes
__global__ __launch_bounds__(256) void k_fc(const char* __restrict__ a2,
                                            const unsigned* __restrict__ fcp,
                                            const float* __restrict__ fcb,
                                            float* __restrict__ out) {
    int t = blockIdx.x*256 + threadIdx.x;  // < 81920
    int b = t / 10, j = t % 10;
    const unsigned* ar = (const unsigned*)(a2 + (size_t)b*1568);
    const unsigned* wr = fcp + j*392;
    int p = 0;
    for (int g = 0; g < 392; ++g)
        p += __popc((ar[g] ^ wr[g]) & 0x02020202u);
    out[t] = (float)(1568 - 2*p) + fcb[j];
}

// ---------------------------------------------------------------------------
extern "C" void kernel_launch(void* const* d_in, const int* in_sizes, int n_in,
                              void* d_out, int out_size, void* d_ws, size_t ws_size,
                              hipStream_t stream) {
    const float* x    = (const float*)d_in[0];
    const float* w1   = (const float*)d_in[1];
    const float* b1   = (const float*)d_in[2];
    const float* bn1g = (const float*)d_in[3];
    const float* bn1b = (const float*)d_in[4];
    const float* w2   = (const float*)d_in[5];
    const float* b2   = (const float*)d_in[6];
    const float* bn2g = (const float*)d_in[7];
    const float* bn2b = (const float*)d_in[8];
    const float* fcw  = (const float*)d_in[9];
    const float* fcb  = (const float*)d_in[10];
    float* out = (float*)d_out;

    char* ws = (char*)d_ws;
    size_t cur = 0;
    auto alloc = [&](size_t sz) {
        size_t o = cur;
        cur += (sz + 255) & ~(size_t)255;
        return o;
    };
    unsigned*       w1s      = (unsigned*)(ws + alloc(16 * 4));
    unsigned short* w2b      = (unsigned short*)(ws + alloc(800 * 2));
    unsigned*       w2p      = (unsigned*)(ws + alloc(416 * 4));
    unsigned short* w2k      = (unsigned short*)(ws + alloc(800 * 2));
    unsigned*       fcp      = (unsigned*)(ws + alloc(3920 * 4));
    unsigned*       selb     = (unsigned*)(ws + alloc(2 * 4));
    double*         thr1     = (double*)(ws + alloc(16 * 8));
    int*            mode1    = (int*)(ws + alloc(16 * 4));
    double*         thr2     = (double*)(ws + alloc(32 * 8));
    int*            mode2    = (int*)(ws + alloc(32 * 4));
    double*         partial1 = (double*)(ws + alloc((size_t)C1S_BLOCKS * 32 * 8));
    int*            partial2 = (int*)(ws + alloc((size_t)C2F_BLOCKS * 64 * 4));
    unsigned short* a1b      = (unsigned short*)(ws + alloc((size_t)NPOOL1 * 2));
    short*          ext2     = (short*)(ws + alloc((size_t)C2 * NPOOL2 * 2));
    char*           a2       = (char*)(ws + alloc((size_t)BATCH * 1568));

    k_prep<<<1, 256, 0, stream>>>(w1, w2, fcw, bn1g, bn2g,
                                  w1s, w2b, w2p, w2k, fcp, selb);
    k_conv1_stats2<<<C1S_BLOCKS, 256, 0, stream>>>(x, w1s, b1, partial1);
    k_finalize1<<<16, 256, 0, stream>>>(partial1, C1S_BLOCKS, bn1g, bn1b, thr1, mode1);
    k_a1_fast<<<A1_BLOCKS, 256, 0, stream>>>(x, w1s, b1, thr1, mode1, a1b);
    k_conv2_fused<<<C2F_BLOCKS, 256, 0, stream>>>(a1b, w2p, w2k, selb, ext2, partial2);
    k_finalize2i<<<32, 256, 0, stream>>>(partial2, C2F_BLOCKS, b2, bn2g, bn2b, thr2, mode2);
    k_sign2<<<NPOOL2/256, 256, 0, stream>>>(ext2, b2, thr2, mode2, a2);
    k_fc<<<320, 256, 0, stream>>>(a2, fcp, fcb, out);
}

// Round 6
// 296.245 us; speedup vs baseline: 1.5149x; 1.5149x over previous
//
#include <hip/hip_runtime.h>
#include <stdint.h>

#define BATCH 8192
#define H1 28
#define W1 28
#define C1 16
#define P1 14
#define C2 32
#define P2 7

#define NPIX1  (BATCH*H1*W1)    // 6,422,528
#define NPOOL1 (BATCH*P1*P1)    // 1,605,632
#define NPOOL2 (BATCH*P2*P2)    // 401,408

#define MM2_ITERS  8
#define MM2_BLOCKS 784          // NPOOL1 / (256*8)
#define A1S_BLOCKS 6272         // NPOOL1/256
#define C2F_BLOCKS 6272         // NPOOL2*4/256 (quarter channel split)

typedef float f32x2 __attribute__((ext_vector_type(2)));

// ---------------------------------------------------------------------------
// Weight prep.
//  w1s : 25-bit sign masks [16]
//  w2b : u16 channel masks [32][25] (bit ci = w>=0)
//  w2p : packed tap-pairs  [32][13]
//  w2k : border-correction K table [25 classes][32], K = 16*nv + 2*C_invalid
//  fcp : packed sign bytes [10][392]
//  selb: {g1<0 bits, g2<0 bits}
// ---------------------------------------------------------------------------
__global__ __launch_bounds__(256) void k_prep(const float* __restrict__ w1,
                                              const float* __restrict__ w2,
                                              const float* __restrict__ fcw,
                                              const float* __restrict__ g1,
                                              const float* __restrict__ g2,
                                              unsigned* __restrict__ w1s,
                                              unsigned short* __restrict__ w2b,
                                              unsigned* __restrict__ w2p,
                                              unsigned short* __restrict__ w2k,
                                              unsigned* __restrict__ fcp,
                                              unsigned* __restrict__ selb) {
    for (int c = threadIdx.x; c < 16; c += blockDim.x) {
        unsigned sb = 0;
        for (int i = 0; i < 25; ++i)
            if (w1[c*25 + i] < 0.f) sb |= 1u << i;
        w1s[c] = sb;
    }
    for (int i = threadIdx.x; i < 800; i += blockDim.x) {
        int co = i / 25, kk = i % 25;
        unsigned m = 0;
        for (int ci = 0; ci < 16; ++ci)
            if (w2[co*400 + ci*25 + kk] >= 0.f) m |= 1u << ci;
        w2b[i] = (unsigned short)m;
    }
    for (int i = threadIdx.x; i < 32*13; i += blockDim.x) {
        int co = i / 13, j = i % 13;
        int k1, k2;
        if (j < 10)      { k1 = (j/2)*5 + (j&1)*2; k2 = k1 + 1; }
        else if (j == 10){ k1 = 4;  k2 = 9;  }
        else if (j == 11){ k1 = 14; k2 = 19; }
        else             { k1 = 24; k2 = -1; }
        unsigned lo = 0, hi = 0;
        for (int ci = 0; ci < 16; ++ci) {
            if (w2[co*400 + ci*25 + k1] >= 0.f) lo |= 1u << ci;
            if (k2 >= 0 && w2[co*400 + ci*25 + k2] >= 0.f) hi |= 1u << ci;
        }
        w2p[i] = lo | (hi << 16);
    }
    for (int i = threadIdx.x; i < 3920; i += blockDim.x) {
        int j = i / 392, g = i % 392;
        unsigned v = 0;
        for (int by = 0; by < 4; ++by) {
            int k = g*4 + by;
            unsigned char s = (fcw[j*1568 + k] >= 0.f) ? 0x01 : 0xFF;
            v |= ((unsigned)s) << (8*by);
        }
        fcp[i] = v;
    }
    if (threadIdx.x == 0) {
        unsigned s1 = 0, s2 = 0;
        for (int c = 0; c < 16; ++c) if (g1[c] < 0.f) s1 |= 1u << c;
        for (int c = 0; c < 32; ++c) if (g2[c] < 0.f) s2 |= 1u << c;
        selb[0] = s1; selb[1] = s2;
    }
    __syncthreads();   // w2b ready -> build K table
    {
        const int lo5[5] = {2,1,0,0,0};
        const int hi5[5] = {4,4,4,3,2};
        for (int i = threadIdx.x; i < 800; i += blockDim.x) {
            int cls = i >> 5, co = i & 31;
            int rc = cls / 5, cc = cls % 5;
            int rlo = lo5[rc], rhi = hi5[rc], clo = lo5[cc], chi = hi5[cc];
            int C = 0;
            for (int ky = 0; ky < 5; ++ky)
                for (int kx = 0; kx < 5; ++kx)
                    if (ky < rlo || ky > rhi || kx < clo || kx > chi)
                        C += __popc((unsigned)w2b[co*25 + ky*5 + kx]);
            int nv = (rhi - rlo + 1) * (chi - clo + 1);
            w2k[i] = (unsigned short)(16*nv + 2*C);
        }
    }
}

// ---------------------------------------------------------------------------
// conv1 once: 16 ch/thread (wave-uniform -> masks live in SGPRs), 8 pooled
// positions/thread. Per position-channel: 25 pk-fma conv (exact f32 chains,
// tap order 0..24), pk bias add, mode-selected pooled extremum -> ext1 (f32),
// stats squared/paired in f32-pk then folded to f64 ONCE per position.
// One 6-level f64 butterfly per thread (amortized over 8 positions).
// ---------------------------------------------------------------------------
__global__ __launch_bounds__(256, 3) void k_conv1_mm2(const float* __restrict__ x,
                                                      const unsigned* __restrict__ w1s,
                                                      const float* __restrict__ b1,
                                                      const unsigned* __restrict__ selb,
                                                      float* __restrict__ ext1,
                                                      double* __restrict__ partial1) {
    unsigned selbs = __builtin_amdgcn_readfirstlane(selb[0]);
    double s[16], q[16];
#pragma unroll
    for (int c = 0; c < 16; ++c) { s[c] = 0.0; q[c] = 0.0; }

#pragma unroll 1
    for (int it = 0; it < MM2_ITERS; ++it) {
        int p = blockIdx.x*(256*MM2_ITERS) + it*256 + threadIdx.x;
        int b = p / (P1*P1);
        int r = p % (P1*P1);
        int py = r / P1, px = r % P1;
        const float* xb = x + (size_t)b * (H1*W1);

        float xd[36];
#pragma unroll
        for (int dy = 0; dy < 6; ++dy) {
            int iy = 2*py + dy - 2;
#pragma unroll
            for (int dx = 0; dx < 6; ++dx) {
                int ix = 2*px + dx - 2;
                xd[dy*6 + dx] = (iy >= 0 && iy < H1 && ix >= 0 && ix < W1)
                              ? xb[iy*W1 + ix] : 0.f;
            }
        }

#pragma unroll
        for (int c = 0; c < 16; ++c) {
            unsigned sb = __builtin_amdgcn_readfirstlane(w1s[c]);
            f32x2 y01 = {0.f, 0.f}, y23 = {0.f, 0.f};
#pragma unroll
            for (int ky = 0; ky < 5; ++ky) {
#pragma unroll
                for (int kx = 0; kx < 5; ++kx) {
                    float m = __uint_as_float(0x3F800000u ^
                                (((sb >> (ky*5 + kx)) & 1u) << 31));
                    f32x2 x01 = { xd[ ky   *6 + kx], xd[ ky   *6 + kx + 1] };
                    f32x2 x23 = { xd[(ky+1)*6 + kx], xd[(ky+1)*6 + kx + 1] };
                    y01 = x01 * m + y01;   // exact: ±x add == fmaf(±1,x,·)
                    y23 = x23 * m + y23;
                }
            }
            float bb = b1[c];
            f32x2 bb2 = {bb, bb};
            y01 = y01 + bb2;               // elementwise == scalar y+bb
            y23 = y23 + bb2;
            float mx = fmaxf(fmaxf(y01.x, y01.y), fmaxf(y23.x, y23.y));
            float mn = fminf(fminf(y01.x, y01.y), fminf(y23.x, y23.y));
            ext1[(size_t)c*NPOOL1 + p] = ((selbs >> c) & 1u) ? mn : mx;
            // stats: f32-pk partials, f64 fold once per position
            f32x2 sp = y01 + y23;
            f32x2 qp = y01 * y01;
            qp = y23 * y23 + qp;
            s[c] += (double)(sp.x + sp.y);
            q[c] += (double)(qp.x + qp.y);
        }
    }

    __shared__ double lsum[4][16], lsq[4][16];
    int wave = threadIdx.x >> 6, lane = threadIdx.x & 63;
#pragma unroll
    for (int c = 0; c < 16; ++c) {
        double ss = s[c], qq = q[c];
#pragma unroll
        for (int off = 32; off; off >>= 1) {
            ss += __shfl_down(ss, off);
            qq += __shfl_down(qq, off);
        }
        if (lane == 0) { lsum[wave][c] = ss; lsq[wave][c] = qq; }
    }
    __syncthreads();
    if (threadIdx.x < 16) {
        int c = threadIdx.x;
        partial1[(size_t)blockIdx.x*32 + c] =
            lsum[0][c] + lsum[1][c] + lsum[2][c] + lsum[3][c];
    } else if (threadIdx.x < 32) {
        int c = threadIdx.x - 16;
        partial1[(size_t)blockIdx.x*32 + 16 + c] =
            lsq[0][c] + lsq[1][c] + lsq[2][c] + lsq[3][c];
    }
}

// finalize1: reduce partials, per-channel threshold + mode
__global__ __launch_bounds__(256) void k_finalize1(const double* __restrict__ part,
                                                   int nblk,
                                                   const float* __restrict__ g,
                                                   const float* __restrict__ be,
                                                   double* __restrict__ thr,
                                                   int* __restrict__ mode) {
    int c = blockIdx.x;
    double s = 0, q = 0;
    for (int i = threadIdx.x; i < nblk; i += 256) {
        s += part[(size_t)i*32 + c];
        q += part[(size_t)i*32 + 16 + c];
    }
    __shared__ double ls[256], lq[256];
    ls[threadIdx.x] = s; lq[threadIdx.x] = q;
    __syncthreads();
    for (int st = 128; st > 0; st >>= 1) {
        if (threadIdx.x < st) {
            ls[threadIdx.x] += ls[threadIdx.x + st];
            lq[threadIdx.x] += lq[threadIdx.x + st];
        }
        __syncthreads();
    }
    if (threadIdx.x == 0) {
        double N = (double)NPIX1;
        double m = ls[0] / N;
        double var = lq[0] / N - m*m;
        double gamma = (double)g[c], beta = (double)be[c];
        double sc = gamma / sqrt(var + 1e-5);
        int md; double tt = 0.0;
        if (sc > 0)      { md = 0; tt = m - beta / sc; }
        else if (sc < 0) { md = 1; tt = m - beta / sc; }
        else             { md = (beta >= 0) ? 2 : 3; }
        thr[c] = tt; mode[c] = md;
    }
}

// signs from stored extrema (memory-bound)
__global__ __launch_bounds__(256) void k_sign1(const float* __restrict__ ext1,
                                               const double* __restrict__ thr,
                                               const int* __restrict__ mode,
                                               unsigned short* __restrict__ a1b) {
    int t = blockIdx.x*256 + threadIdx.x;
    unsigned bits = 0;
#pragma unroll
    for (int c = 0; c < 16; ++c) {
        float v = ext1[(size_t)c*NPOOL1 + t];
        int md = mode[c]; double tt = thr[c];
        bool plus = (md == 0) ? ((double)v >= tt)
                  : (md == 1) ? ((double)v <= tt)
                  : (md == 2);
        bits |= (plus ? 1u : 0u) << c;
    }
    a1b[t] = (unsigned short)bits;
}

// ---------------------------------------------------------------------------
// conv2 fused: LDS-staged zero-padded images + K-corrected XNOR-popcount.
// Block: 64 pooled positions x 4 channel-quarters. Stages <=3 images.
// y = K[class][co] - 2*popc_full  (exact integers).
// ---------------------------------------------------------------------------
__global__ __launch_bounds__(256) void k_conv2_fused(const unsigned short* __restrict__ a1b,
                                                     const unsigned* __restrict__ w2p,
                                                     const unsigned short* __restrict__ w2k,
                                                     const unsigned* __restrict__ selb,
                                                     short* __restrict__ ext2,
                                                     int* __restrict__ partial2) {
    __shared__ unsigned short raw[3*18*18];
    __shared__ unsigned sw[32*13];
    __shared__ unsigned short kt[25*32];
    __shared__ int lsum[4][32], lsq[4][32];

    const int B0 = blockIdx.x * 64;
    const int i0 = B0 / 49;
    const int ilast = (B0 + 63) / 49;
    const int icnt = ilast - i0 + 1;       // 2 or 3

    for (int i = threadIdx.x; i < 416; i += 256) sw[i] = w2p[i];
    for (int i = threadIdx.x; i < 800; i += 256) kt[i] = w2k[i];
    {   // zero padded tiles
        unsigned* rz = (unsigned*)raw;
        int n32 = icnt * 162;
        for (int i = threadIdx.x; i < n32; i += 256) rz[i] = 0u;
    }
    __syncthreads();
    {   // fill valid interior
        int n = icnt * 196;
        for (int e = threadIdx.x; e < n; e += 256) {
            int img = e / 196, lin = e % 196;
            unsigned short v = a1b[(size_t)(i0 + img)*196 + lin];
            int py = lin / 14, px = lin % 14;
            raw[(img*18 + py + 2)*18 + px + 2] = v;
        }
    }
    __syncthreads();

    const int quarter = threadIdx.x & 3;
    const int c0 = quarter << 3;
    const int t = B0 + (threadIdx.x >> 2);
    const int img = t / 49 - i0;
    const int r = t % 49;
    const int qy = r / 7, qx = r % 7;
    const unsigned selbs = __builtin_amdgcn_readfirstlane(selb[1]);

    unsigned am[36];
#pragma unroll
    for (int wy = 0; wy < 6; ++wy)
#pragma unroll
        for (int wx = 0; wx < 6; ++wx)
            am[wy*6 + wx] = (unsigned)raw[(img*18 + 2*qy + wy)*18 + 2*qx + wx];

    int s[8], q[8], mx[8], mn[8];
#pragma unroll
    for (int i = 0; i < 8; ++i) { s[i]=0; q[i]=0; mx[i]=-1000000; mn[i]=1000000; }

#pragma unroll
    for (int sp = 0; sp < 4; ++sp) {
        const int sy = sp >> 1, sx = sp & 1;
        const int oy = 2*qy + sy, ox = 2*qx + sx;
        const int rcls = (oy < 2) ? oy : ((oy > 11) ? oy - 9 : 2);
        const int ccls = (ox < 2) ? ox : ((ox > 11) ? ox - 9 : 2);
        const int kbase = (rcls*5 + ccls) * 32 + c0;

        unsigned ap[13];
#pragma unroll
        for (int ky = 0; ky < 5; ++ky) {
            ap[ky*2+0] = am[(sy+ky)*6 + sx+0] | (am[(sy+ky)*6 + sx+1] << 16);
            ap[ky*2+1] = am[(sy+ky)*6 + sx+2] | (am[(sy+ky)*6 + sx+3] << 16);
        }
        ap[10] = am[(sy+0)*6 + sx+4] | (am[(sy+1)*6 + sx+4] << 16);
        ap[11] = am[(sy+2)*6 + sx+4] | (am[(sy+3)*6 + sx+4] << 16);
        ap[12] = am[(sy+4)*6 + sx+4];

#pragma unroll
        for (int cl = 0; cl < 8; ++cl) {
            const unsigned* wr = sw + (c0 + cl)*13;
            int p = 0;
#pragma unroll
            for (int j = 0; j < 13; ++j)
                p += __popc(ap[j] ^ wr[j]);
            int y = (int)kt[kbase + cl] - 2*p;
            s[cl] += y; q[cl] += y*y;
            mx[cl] = (y > mx[cl]) ? y : mx[cl];
            mn[cl] = (y < mn[cl]) ? y : mn[cl];
        }
    }

#pragma unroll
    for (int cl = 0; cl < 8; ++cl) {
        int co = c0 + cl;
        int sel = (selbs >> co) & 1;
        ext2[(size_t)co*NPOOL2 + t] = (short)(sel ? mn[cl] : mx[cl]);
    }

    int wave = threadIdx.x >> 6, lane = threadIdx.x & 63;
#pragma unroll
    for (int cl = 0; cl < 8; ++cl) {
        int ss = s[cl], qq = q[cl];
#pragma unroll
        for (int off = 32; off >= 4; off >>= 1) {   // quarter-preserving
            ss += __shfl_down(ss, off);
            qq += __shfl_down(qq, off);
        }
        if (lane < 4) {
            lsum[wave][lane*8 + cl] = ss;
            lsq[wave][lane*8 + cl]  = qq;
        }
    }
    __syncthreads();
    if (threadIdx.x < 32) {
        int co = threadIdx.x;
        partial2[(size_t)blockIdx.x*64 + co] =
            lsum[0][co] + lsum[1][co] + lsum[2][co] + lsum[3][co];
    } else if (threadIdx.x < 64) {
        int co = threadIdx.x - 32;
        partial2[(size_t)blockIdx.x*64 + 32 + co] =
            lsq[0][co] + lsq[1][co] + lsq[2][co] + lsq[3][co];
    }
}

// finalize2 (int partials); thr on (y + bias) scale
__global__ __launch_bounds__(256) void k_finalize2i(const int* __restrict__ part,
                                                    int nblk,
                                                    const float* __restrict__ b2,
                                                    const float* __restrict__ g,
                                                    const float* __restrict__ be,
                                                    double* __restrict__ thr,
                                                    int* __restrict__ mode) {
    int c = blockIdx.x;
    long long s = 0, q = 0;
    for (int i = threadIdx.x; i < nblk; i += 256) {
        s += (long long)part[(size_t)i*64 + c];
        q += (long long)part[(size_t)i*64 + 32 + c];
    }
    __shared__ long long ls[256], lq[256];
    ls[threadIdx.x] = s; lq[threadIdx.x] = q;
    __syncthreads();
    for (int st = 128; st > 0; st >>= 1) {
        if (threadIdx.x < st) {
            ls[threadIdx.x] += ls[threadIdx.x + st];
            lq[threadIdx.x] += lq[threadIdx.x + st];
        }
        __syncthreads();
    }
    if (threadIdx.x == 0) {
        double N = (double)(BATCH * P1 * P1);
        double my = (double)ls[0] / N;
        double var = (double)lq[0] / N - my*my;   // bias-shift invariant
        double m = my + (double)b2[c];
        double gamma = (double)g[c], beta = (double)be[c];
        double sc = gamma / sqrt(var + 1e-5);
        int md; double tt = 0.0;
        if (sc > 0)      { md = 0; tt = m - beta / sc; }
        else if (sc < 0) { md = 1; tt = m - beta / sc; }
        else             { md = (beta >= 0) ? 2 : 3; }
        thr[c] = tt; mode[c] = md;
    }
}

// stage-2 signs; emulate fl32(y + b2) exactly before f64 compare
__global__ __launch_bounds__(256) void k_sign2(const short* __restrict__ ext2,
                                               const float* __restrict__ b2,
                                               const double* __restrict__ thr,
                                               const int* __restrict__ mode,
                                               char* __restrict__ a2) {
    int t = blockIdx.x*256 + threadIdx.x;
    int b = t / (P2*P2);
    int r = t % (P2*P2);
#pragma unroll 1
    for (int co = 0; co < 32; ++co) {
        short v = ext2[(size_t)co*NPOOL2 + t];
        float yf = (float)v + b2[co];
        int md = mode[co]; double tt = thr[co];
        bool plus = (md == 0) ? ((double)yf >= tt)
                  : (md == 1) ? ((double)yf <= tt)
                  : (md == 2);
        a2[(size_t)b*1568 + co*49 + r] = plus ? (char)1 : (char)-1;
    }
}

// FC: popcount dot over ±1 bytes
__global__ __launch_bounds__(256) void k_fc(const char* __restrict__ a2,
                                            const unsigned* __restrict__ fcp,
                                            const float* __restrict__ fcb,
                                            float* __restrict__ out) {
    int t = blockIdx.x*256 + threadIdx.x;  // < 81920
    int b = t / 10, j = t % 10;
    const unsigned* ar = (const unsigned*)(a2 + (size_t)b*1568);
    const unsigned* wr = fcp + j*392;
    int p = 0;
    for (int g = 0; g < 392; ++g)
        p += __popc((ar[g] ^ wr[g]) & 0x02020202u);
    out[t] = (float)(1568 - 2*p) + fcb[j];
}

// ---------------------------------------------------------------------------
extern "C" void kernel_launch(void* const* d_in, const int* in_sizes, int n_in,
                              void* d_out, int out_size, void* d_ws, size_t ws_size,
                              hipStream_t stream) {
    const float* x    = (const float*)d_in[0];
    const float* w1   = (const float*)d_in[1];
    const float* b1   = (const float*)d_in[2];
    const float* bn1g = (const float*)d_in[3];
    const float* bn1b = (const float*)d_in[4];
    const float* w2   = (const float*)d_in[5];
    const float* b2   = (const float*)d_in[6];
    const float* bn2g = (const float*)d_in[7];
    const float* bn2b = (const float*)d_in[8];
    const float* fcw  = (const float*)d_in[9];
    const float* fcb  = (const float*)d_in[10];
    float* out = (float*)d_out;

    char* ws = (char*)d_ws;
    size_t cur = 0;
    auto alloc = [&](size_t sz) {
        size_t o = cur;
        cur += (sz + 255) & ~(size_t)255;
        return o;
    };
    unsigned*       w1s      = (unsigned*)(ws + alloc(16 * 4));
    unsigned short* w2b      = (unsigned short*)(ws + alloc(800 * 2));
    unsigned*       w2p      = (unsigned*)(ws + alloc(416 * 4));
    unsigned short* w2k      = (unsigned short*)(ws + alloc(800 * 2));
    unsigned*       fcp      = (unsigned*)(ws + alloc(3920 * 4));
    unsigned*       selb     = (unsigned*)(ws + alloc(2 * 4));
    double*         thr1     = (double*)(ws + alloc(16 * 8));
    int*            mode1    = (int*)(ws + alloc(16 * 4));
    double*         thr2     = (double*)(ws + alloc(32 * 8));
    int*            mode2    = (int*)(ws + alloc(32 * 4));
    double*         partial1 = (double*)(ws + alloc((size_t)MM2_BLOCKS * 32 * 8));
    int*            partial2 = (int*)(ws + alloc((size_t)C2F_BLOCKS * 64 * 4));
    unsigned short* a1b      = (unsigned short*)(ws + alloc((size_t)NPOOL1 * 2));
    char*           a2       = (char*)(ws + alloc((size_t)BATCH * 1568));
    // ext1 (f32, 16*NPOOL1 = 102.8 MB) and ext2 (s16, 32*NPOOL2 = 25.7 MB)
    // have disjoint lifetimes (ext1 dead after k_sign1) -> share one region.
    size_t extoff = alloc((size_t)C1 * NPOOL1 * 4);
    float* ext1 = (float*)(ws + extoff);
    short* ext2 = (short*)(ws + extoff);

    k_prep<<<1, 256, 0, stream>>>(w1, w2, fcw, bn1g, bn2g,
                                  w1s, w2b, w2p, w2k, fcp, selb);
    k_conv1_mm2<<<MM2_BLOCKS, 256, 0, stream>>>(x, w1s, b1, selb, ext1, partial1);
    k_finalize1<<<16, 256, 0, stream>>>(partial1, MM2_BLOCKS, bn1g, bn1b, thr1, mode1);
    k_sign1<<<A1S_BLOCKS, 256, 0, stream>>>(ext1, thr1, mode1, a1b);
    k_conv2_fused<<<C2F_BLOCKS, 256, 0, stream>>>(a1b, w2p, w2k, selb, ext2, partial2);
    k_finalize2i<<<32, 256, 0, stream>>>(partial2, C2F_BLOCKS, b2, bn2g, bn2b, thr2, mode2);
    k_sign2<<<NPOOL2/256, 256, 0, stream>>>(ext2, b2, thr2, mode2, a2);
    k_fc<<<320, 256, 0, stream>>>(a2, fcp, fcb, out);
}

// Round 7
// 279.947 us; speedup vs baseline: 1.6031x; 1.0582x over previous
//
#include <hip/hip_runtime.h>
#include <stdint.h>

#define BATCH 8192
#define H1 28
#define W1 28
#define C1 16
#define P1 14
#define C2 32
#define P2 7

#define NPIX1  (BATCH*H1*W1)    // 6,422,528
#define NPOOL1 (BATCH*P1*P1)    // 1,605,632
#define NPOOL2 (BATCH*P2*P2)    // 401,408

#define MM2_ITERS  4
#define MM2_BLOCKS 1568         // NPOOL1 / (256*4)
#define A1S_BLOCKS 6272         // NPOOL1/256
#define C2F_BLOCKS 6272         // NPOOL2*4/256 (quarter channel split)

typedef float f32x2 __attribute__((ext_vector_type(2)));

// ---------------------------------------------------------------------------
// Weight prep.
//  w1s : 25-bit sign masks [16]
//  w2b : u16 channel masks [32][25] (bit ci = w>=0)
//  w2p : packed tap-pairs  [32][13]
//  w2k : border-correction K table [25 classes][32], K = 16*nv + 2*C_invalid
//  fcp : packed sign bytes [10][392]
//  selb: {g1<0 bits, g2<0 bits}
// ---------------------------------------------------------------------------
__global__ __launch_bounds__(256) void k_prep(const float* __restrict__ w1,
                                              const float* __restrict__ w2,
                                              const float* __restrict__ fcw,
                                              const float* __restrict__ g1,
                                              const float* __restrict__ g2,
                                              unsigned* __restrict__ w1s,
                                              unsigned short* __restrict__ w2b,
                                              unsigned* __restrict__ w2p,
                                              unsigned short* __restrict__ w2k,
                                              unsigned* __restrict__ fcp,
                                              unsigned* __restrict__ selb) {
    for (int c = threadIdx.x; c < 16; c += blockDim.x) {
        unsigned sb = 0;
        for (int i = 0; i < 25; ++i)
            if (w1[c*25 + i] < 0.f) sb |= 1u << i;
        w1s[c] = sb;
    }
    for (int i = threadIdx.x; i < 800; i += blockDim.x) {
        int co = i / 25, kk = i % 25;
        unsigned m = 0;
        for (int ci = 0; ci < 16; ++ci)
            if (w2[co*400 + ci*25 + kk] >= 0.f) m |= 1u << ci;
        w2b[i] = (unsigned short)m;
    }
    for (int i = threadIdx.x; i < 32*13; i += blockDim.x) {
        int co = i / 13, j = i % 13;
        int k1, k2;
        if (j < 10)      { k1 = (j/2)*5 + (j&1)*2; k2 = k1 + 1; }
        else if (j == 10){ k1 = 4;  k2 = 9;  }
        else if (j == 11){ k1 = 14; k2 = 19; }
        else             { k1 = 24; k2 = -1; }
        unsigned lo = 0, hi = 0;
        for (int ci = 0; ci < 16; ++ci) {
            if (w2[co*400 + ci*25 + k1] >= 0.f) lo |= 1u << ci;
            if (k2 >= 0 && w2[co*400 + ci*25 + k2] >= 0.f) hi |= 1u << ci;
        }
        w2p[i] = lo | (hi << 16);
    }
    for (int i = threadIdx.x; i < 3920; i += blockDim.x) {
        int j = i / 392, g = i % 392;
        unsigned v = 0;
        for (int by = 0; by < 4; ++by) {
            int k = g*4 + by;
            unsigned char s = (fcw[j*1568 + k] >= 0.f) ? 0x01 : 0xFF;
            v |= ((unsigned)s) << (8*by);
        }
        fcp[i] = v;
    }
    if (threadIdx.x == 0) {
        unsigned s1 = 0, s2 = 0;
        for (int c = 0; c < 16; ++c) if (g1[c] < 0.f) s1 |= 1u << c;
        for (int c = 0; c < 32; ++c) if (g2[c] < 0.f) s2 |= 1u << c;
        selb[0] = s1; selb[1] = s2;
    }
    __syncthreads();   // w2b ready -> build K table
    {
        const int lo5[5] = {2,1,0,0,0};
        const int hi5[5] = {4,4,4,3,2};
        for (int i = threadIdx.x; i < 800; i += blockDim.x) {
            int cls = i >> 5, co = i & 31;
            int rc = cls / 5, cc = cls % 5;
            int rlo = lo5[rc], rhi = hi5[rc], clo = lo5[cc], chi = hi5[cc];
            int C = 0;
            for (int ky = 0; ky < 5; ++ky)
                for (int kx = 0; kx < 5; ++kx)
                    if (ky < rlo || ky > rhi || kx < clo || kx > chi)
                        C += __popc((unsigned)w2b[co*25 + ky*5 + kx]);
            int nv = (rhi - rlo + 1) * (chi - clo + 1);
            w2k[i] = (unsigned short)(16*nv + 2*C);
        }
    }
}

// ---------------------------------------------------------------------------
// conv1 once: 16 ch/thread (wave-uniform -> masks live in SGPRs), 4 pooled
// positions/thread (1568 blocks -> ~24 waves/CU for latency hiding).
// x loads: 3x 8B-aligned dwordx2 per window row + cndmask zero-selects
// (values bit-identical to the scalar predicated loads).
// Per position-channel: 25 pk-fma conv (exact f32 chains, tap order 0..24),
// pk bias add, mode-selected pooled extremum -> ext1 (f32), stats squared in
// f32-pk then folded to f64 once per position. One butterfly per thread.
// ---------------------------------------------------------------------------
__global__ __launch_bounds__(256, 3) void k_conv1_mm2(const float* __restrict__ x,
                                                      const unsigned* __restrict__ w1s,
                                                      const float* __restrict__ b1,
                                                      const unsigned* __restrict__ selb,
                                                      float* __restrict__ ext1,
                                                      double* __restrict__ partial1) {
    unsigned selbs = __builtin_amdgcn_readfirstlane(selb[0]);
    double s[16], q[16];
#pragma unroll
    for (int c = 0; c < 16; ++c) { s[c] = 0.0; q[c] = 0.0; }

#pragma unroll 1
    for (int it = 0; it < MM2_ITERS; ++it) {
        int p = blockIdx.x*(256*MM2_ITERS) + it*256 + threadIdx.x;
        int b = p / (P1*P1);
        int r = p % (P1*P1);
        int py = r / P1, px = r % P1;
        const float* xb = x + (size_t)b * (H1*W1);

        // window columns: ix0..ix0+5, ix0 = 2*px-2 (even). Only px==0 (left
        // pair) and px==13 (right pair) touch OOB columns; middle pair always
        // valid. 8B alignment: image/row/column offsets all even floats.
        const int ix0 = 2*px - 2;
        const bool cL = (px == 0), cR = (px == 13);
        const int ix0c = cL ? 0 : ix0;
        const int ix4c = cR ? 22 : ix0 + 4;

        float xd[36];
#pragma unroll
        for (int dy = 0; dy < 6; ++dy) {
            int iy = 2*py + dy - 2;
            bool rv = (iy >= 0) && (iy < H1);
            int iyc = rv ? iy : 0;
            const float* rp = xb + iyc*W1;
            f32x2 p0 = *(const f32x2*)(rp + ix0c);
            f32x2 p1 = *(const f32x2*)(rp + ix0 + 2);
            f32x2 p2 = *(const f32x2*)(rp + ix4c);
            bool vL = rv && !cL, vR = rv && !cR;
            xd[dy*6+0] = vL ? p0.x : 0.f;
            xd[dy*6+1] = vL ? p0.y : 0.f;
            xd[dy*6+2] = rv ? p1.x : 0.f;
            xd[dy*6+3] = rv ? p1.y : 0.f;
            xd[dy*6+4] = vR ? p2.x : 0.f;
            xd[dy*6+5] = vR ? p2.y : 0.f;
        }

#pragma unroll
        for (int c = 0; c < 16; ++c) {
            unsigned sb = __builtin_amdgcn_readfirstlane(w1s[c]);
            f32x2 y01 = {0.f, 0.f}, y23 = {0.f, 0.f};
#pragma unroll
            for (int ky = 0; ky < 5; ++ky) {
#pragma unroll
                for (int kx = 0; kx < 5; ++kx) {
                    float m = __uint_as_float(0x3F800000u ^
                                (((sb >> (ky*5 + kx)) & 1u) << 31));
                    f32x2 x01 = { xd[ ky   *6 + kx], xd[ ky   *6 + kx + 1] };
                    f32x2 x23 = { xd[(ky+1)*6 + kx], xd[(ky+1)*6 + kx + 1] };
                    y01 = x01 * m + y01;   // exact: ±x add == fmaf(±1,x,·)
                    y23 = x23 * m + y23;
                }
            }
            float bb = b1[c];
            f32x2 bb2 = {bb, bb};
            y01 = y01 + bb2;               // elementwise == scalar y+bb
            y23 = y23 + bb2;
            float mx = fmaxf(fmaxf(y01.x, y01.y), fmaxf(y23.x, y23.y));
            float mn = fminf(fminf(y01.x, y01.y), fminf(y23.x, y23.y));
            ext1[(size_t)c*NPOOL1 + p] = ((selbs >> c) & 1u) ? mn : mx;
            // stats: f32-pk partials, f64 fold once per position
            f32x2 sp = y01 + y23;
            f32x2 qp = y01 * y01;
            qp = y23 * y23 + qp;
            s[c] += (double)(sp.x + sp.y);
            q[c] += (double)(qp.x + qp.y);
        }
    }

    __shared__ double lsum[4][16], lsq[4][16];
    int wave = threadIdx.x >> 6, lane = threadIdx.x & 63;
#pragma unroll
    for (int c = 0; c < 16; ++c) {
        double ss = s[c], qq = q[c];
#pragma unroll
        for (int off = 32; off; off >>= 1) {
            ss += __shfl_down(ss, off);
            qq += __shfl_down(qq, off);
        }
        if (lane == 0) { lsum[wave][c] = ss; lsq[wave][c] = qq; }
    }
    __syncthreads();
    if (threadIdx.x < 16) {
        int c = threadIdx.x;
        partial1[(size_t)blockIdx.x*32 + c] =
            lsum[0][c] + lsum[1][c] + lsum[2][c] + lsum[3][c];
    } else if (threadIdx.x < 32) {
        int c = threadIdx.x - 16;
        partial1[(size_t)blockIdx.x*32 + 16 + c] =
            lsq[0][c] + lsq[1][c] + lsq[2][c] + lsq[3][c];
    }
}

// finalize1: reduce partials, per-channel threshold + mode
__global__ __launch_bounds__(256) void k_finalize1(const double* __restrict__ part,
                                                   int nblk,
                                                   const float* __restrict__ g,
                                                   const float* __restrict__ be,
                                                   double* __restrict__ thr,
                                                   int* __restrict__ mode) {
    int c = blockIdx.x;
    double s = 0, q = 0;
    for (int i = threadIdx.x; i < nblk; i += 256) {
        s += part[(size_t)i*32 + c];
        q += part[(size_t)i*32 + 16 + c];
    }
    __shared__ double ls[256], lq[256];
    ls[threadIdx.x] = s; lq[threadIdx.x] = q;
    __syncthreads();
    for (int st = 128; st > 0; st >>= 1) {
        if (threadIdx.x < st) {
            ls[threadIdx.x] += ls[threadIdx.x + st];
            lq[threadIdx.x] += lq[threadIdx.x + st];
        }
        __syncthreads();
    }
    if (threadIdx.x == 0) {
        double N = (double)NPIX1;
        double m = ls[0] / N;
        double var = lq[0] / N - m*m;
        double gamma = (double)g[c], beta = (double)be[c];
        double sc = gamma / sqrt(var + 1e-5);
        int md; double tt = 0.0;
        if (sc > 0)      { md = 0; tt = m - beta / sc; }
        else if (sc < 0) { md = 1; tt = m - beta / sc; }
        else             { md = (beta >= 0) ? 2 : 3; }
        thr[c] = tt; mode[c] = md;
    }
}

// signs from stored extrema (memory-bound)
__global__ __launch_bounds__(256) void k_sign1(const float* __restrict__ ext1,
                                               const double* __restrict__ thr,
                                               const int* __restrict__ mode,
                                               unsigned short* __restrict__ a1b) {
    int t = blockIdx.x*256 + threadIdx.x;
    unsigned bits = 0;
#pragma unroll
    for (int c = 0; c < 16; ++c) {
        float v = ext1[(size_t)c*NPOOL1 + t];
        int md = mode[c]; double tt = thr[c];
        bool plus = (md == 0) ? ((double)v >= tt)
                  : (md == 1) ? ((double)v <= tt)
                  : (md == 2);
        bits |= (plus ? 1u : 0u) << c;
    }
    a1b[t] = (unsigned short)bits;
}

// ---------------------------------------------------------------------------
// conv2 fused: LDS-staged zero-padded images + K-corrected XNOR-popcount.
// Block: 64 pooled positions x 4 channel-quarters. Stages <=3 images.
// y = K[class][co] - 2*popc_full  (exact integers).
// ---------------------------------------------------------------------------
__global__ __launch_bounds__(256) void k_conv2_fused(const unsigned short* __restrict__ a1b,
                                                     const unsigned* __restrict__ w2p,
                                                     const unsigned short* __restrict__ w2k,
                                                     const unsigned* __restrict__ selb,
                                                     short* __restrict__ ext2,
                                                     int* __restrict__ partial2) {
    __shared__ unsigned short raw[3*18*18];
    __shared__ unsigned sw[32*13];
    __shared__ unsigned short kt[25*32];
    __shared__ int lsum[4][32], lsq[4][32];

    const int B0 = blockIdx.x * 64;
    const int i0 = B0 / 49;
    const int ilast = (B0 + 63) / 49;
    const int icnt = ilast - i0 + 1;       // 2 or 3

    for (int i = threadIdx.x; i < 416; i += 256) sw[i] = w2p[i];
    for (int i = threadIdx.x; i < 800; i += 256) kt[i] = w2k[i];
    {   // zero padded tiles
        unsigned* rz = (unsigned*)raw;
        int n32 = icnt * 162;
        for (int i = threadIdx.x; i < n32; i += 256) rz[i] = 0u;
    }
    __syncthreads();
    {   // fill valid interior
        int n = icnt * 196;
        for (int e = threadIdx.x; e < n; e += 256) {
            int img = e / 196, lin = e % 196;
            unsigned short v = a1b[(size_t)(i0 + img)*196 + lin];
            int py = lin / 14, px = lin % 14;
            raw[(img*18 + py + 2)*18 + px + 2] = v;
        }
    }
    __syncthreads();

    const int quarter = threadIdx.x & 3;
    const int c0 = quarter << 3;
    const int t = B0 + (threadIdx.x >> 2);
    const int img = t / 49 - i0;
    const int r = t % 49;
    const int qy = r / 7, qx = r % 7;
    const unsigned selbs = __builtin_amdgcn_readfirstlane(selb[1]);

    unsigned am[36];
#pragma unroll
    for (int wy = 0; wy < 6; ++wy)
#pragma unroll
        for (int wx = 0; wx < 6; ++wx)
            am[wy*6 + wx] = (unsigned)raw[(img*18 + 2*qy + wy)*18 + 2*qx + wx];

    int s[8], q[8], mx[8], mn[8];
#pragma unroll
    for (int i = 0; i < 8; ++i) { s[i]=0; q[i]=0; mx[i]=-1000000; mn[i]=1000000; }

#pragma unroll
    for (int sp = 0; sp < 4; ++sp) {
        const int sy = sp >> 1, sx = sp & 1;
        const int oy = 2*qy + sy, ox = 2*qx + sx;
        const int rcls = (oy < 2) ? oy : ((oy > 11) ? oy - 9 : 2);
        const int ccls = (ox < 2) ? ox : ((ox > 11) ? ox - 9 : 2);
        const int kbase = (rcls*5 + ccls) * 32 + c0;

        unsigned ap[13];
#pragma unroll
        for (int ky = 0; ky < 5; ++ky) {
            ap[ky*2+0] = am[(sy+ky)*6 + sx+0] | (am[(sy+ky)*6 + sx+1] << 16);
            ap[ky*2+1] = am[(sy+ky)*6 + sx+2] | (am[(sy+ky)*6 + sx+3] << 16);
        }
        ap[10] = am[(sy+0)*6 + sx+4] | (am[(sy+1)*6 + sx+4] << 16);
        ap[11] = am[(sy+2)*6 + sx+4] | (am[(sy+3)*6 + sx+4] << 16);
        ap[12] = am[(sy+4)*6 + sx+4];

#pragma unroll
        for (int cl = 0; cl < 8; ++cl) {
            const unsigned* wr = sw + (c0 + cl)*13;
            int p = 0;
#pragma unroll
            for (int j = 0; j < 13; ++j)
                p += __popc(ap[j] ^ wr[j]);
            int y = (int)kt[kbase + cl] - 2*p;
            s[cl] += y; q[cl] += y*y;
            mx[cl] = (y > mx[cl]) ? y : mx[cl];
            mn[cl] = (y < mn[cl]) ? y : mn[cl];
        }
    }

#pragma unroll
    for (int cl = 0; cl < 8; ++cl) {
        int co = c0 + cl;
        int sel = (selbs >> co) & 1;
        ext2[(size_t)co*NPOOL2 + t] = (short)(sel ? mn[cl] : mx[cl]);
    }

    int wave = threadIdx.x >> 6, lane = threadIdx.x & 63;
#pragma unroll
    for (int cl = 0; cl < 8; ++cl) {
        int ss = s[cl], qq = q[cl];
#pragma unroll
        for (int off = 32; off >= 4; off >>= 1) {   // quarter-preserving
            ss += __shfl_down(ss, off);
            qq += __shfl_down(qq, off);
        }
        if (lane < 4) {
            lsum[wave][lane*8 + cl] = ss;
            lsq[wave][lane*8 + cl]  = qq;
        }
    }
    __syncthreads();
    if (threadIdx.x < 32) {
        int co = threadIdx.x;
        partial2[(size_t)blockIdx.x*64 + co] =
            lsum[0][co] + lsum[1][co] + lsum[2][co] + lsum[3][co];
    } else if (threadIdx.x < 64) {
        int co = threadIdx.x - 32;
        partial2[(size_t)blockIdx.x*64 + 32 + co] =
            lsq[0][co] + lsq[1][co] + lsq[2][co] + lsq[3][co];
    }
}

// finalize2 (int partials); thr on (y + bias) scale
__global__ __launch_bounds__(256) void k_finalize2i(const int* __restrict__ part,
                                                    int nblk,
                                                    const float* __restrict__ b2,
                                                    const float* __restrict__ g,
                                                    const float* __restrict__ be,
                                                    double* __restrict__ thr,
                                                    int* __restrict__ mode) {
    int c = blockIdx.x;
    long long s = 0, q = 0;
    for (int i = threadIdx.x; i < nblk; i += 256) {
        s += (long long)part[(size_t)i*64 + c];
        q += (long long)part[(size_t)i*64 + 32 + c];
    }
    __shared__ long long ls[256], lq[256];
    ls[threadIdx.x] = s; lq[threadIdx.x] = q;
    __syncthreads();
    for (int st = 128; st > 0; st >>= 1) {
        if (threadIdx.x < st) {
            ls[threadIdx.x] += ls[threadIdx.x + st];
            lq[threadIdx.x] += lq[threadIdx.x + st];
        }
        __syncthreads();
    }
    if (threadIdx.x == 0) {
        double N = (double)(BATCH * P1 * P1);
        double my = (double)ls[0] / N;
        double var = (double)lq[0] / N - my*my;   // bias-shift invariant
        double m = my + (double)b2[c];
        double gamma = (double)g[c], beta = (double)be[c];
        double sc = gamma / sqrt(var + 1e-5);
        int md; double tt = 0.0;
        if (sc > 0)      { md = 0; tt = m - beta / sc; }
        else if (sc < 0) { md = 1; tt = m - beta / sc; }
        else             { md = (beta >= 0) ? 2 : 3; }
        thr[c] = tt; mode[c] = md;
    }
}

// stage-2 signs; emulate fl32(y + b2) exactly before f64 compare
__global__ __launch_bounds__(256) void k_sign2(const short* __restrict__ ext2,
                                               const float* __restrict__ b2,
                                               const double* __restrict__ thr,
                                               const int* __restrict__ mode,
                                               char* __restrict__ a2) {
    int t = blockIdx.x*256 + threadIdx.x;
    int b = t / (P2*P2);
    int r = t % (P2*P2);
#pragma unroll 1
    for (int co = 0; co < 32; ++co) {
        short v = ext2[(size_t)co*NPOOL2 + t];
        float yf = (float)v + b2[co];
        int md = mode[co]; double tt = thr[co];
        bool plus = (md == 0) ? ((double)yf >= tt)
                  : (md == 1) ? ((double)yf <= tt)
                  : (md == 2);
        a2[(size_t)b*1568 + co*49 + r] = plus ? (char)1 : (char)-1;
    }
}

// FC: popcount dot over ±1 bytes
__global__ __launch_bounds__(256) void k_fc(const char* __restrict__ a2,
                                            const unsigned* __restrict__ fcp,
                                            const float* __restrict__ fcb,
                                            float* __restrict__ out) {
    int t = blockIdx.x*256 + threadIdx.x;  // < 81920
    int b = t / 10, j = t % 10;
    const unsigned* ar = (const unsigned*)(a2 + (size_t)b*1568);
    const unsigned* wr = fcp + j*392;
    int p = 0;
    for (int g = 0; g < 392; ++g)
        p += __popc((ar[g] ^ wr[g]) & 0x02020202u);
    out[t] = (float)(1568 - 2*p) + fcb[j];
}

// ---------------------------------------------------------------------------
extern "C" void kernel_launch(void* const* d_in, const int* in_sizes, int n_in,
                              void* d_out, int out_size, void* d_ws, size_t ws_size,
                              hipStream_t stream) {
    const float* x    = (const float*)d_in[0];
    const float* w1   = (const float*)d_in[1];
    const float* b1   = (const float*)d_in[2];
    const float* bn1g = (const float*)d_in[3];
    const float* bn1b = (const float*)d_in[4];
    const float* w2   = (const float*)d_in[5];
    const float* b2   = (const float*)d_in[6];
    const float* bn2g = (const float*)d_in[7];
    const float* bn2b = (const float*)d_in[8];
    const float* fcw  = (const float*)d_in[9];
    const float* fcb  = (const float*)d_in[10];
    float* out = (float*)d_out;

    char* ws = (char*)d_ws;
    size_t cur = 0;
    auto alloc = [&](size_t sz) {
        size_t o = cur;
        cur += (sz + 255) & ~(size_t)255;
        return o;
    };
    unsigned*       w1s      = (unsigned*)(ws + alloc(16 * 4));
    unsigned short* w2b      = (unsigned short*)(ws + alloc(800 * 2));
    unsigned*       w2p      = (unsigned*)(ws + alloc(416 * 4));
    unsigned short* w2k      = (unsigned short*)(ws + alloc(800 * 2));
    unsigned*       fcp      = (unsigned*)(ws + alloc(3920 * 4));
    unsigned*       selb     = (unsigned*)(ws + alloc(2 * 4));
    double*         thr1     = (double*)(ws + alloc(16 * 8));
    int*            mode1    = (int*)(ws + alloc(16 * 4));
    double*         thr2     = (double*)(ws + alloc(32 * 8));
    int*            mode2    = (int*)(ws + alloc(32 * 4));
    double*         partial1 = (double*)(ws + alloc((size_t)MM2_BLOCKS * 32 * 8));
    int*            partial2 = (int*)(ws + alloc((size_t)C2F_BLOCKS * 64 * 4));
    unsigned short* a1b      = (unsigned short*)(ws + alloc((size_t)NPOOL1 * 2));
    char*           a2       = (char*)(ws + alloc((size_t)BATCH * 1568));
    // ext1 (f32, 16*NPOOL1 = 102.8 MB) and ext2 (s16, 32*NPOOL2 = 25.7 MB)
    // have disjoint lifetimes (ext1 dead after k_sign1) -> share one region.
    size_t extoff = alloc((size_t)C1 * NPOOL1 * 4);
    float* ext1 = (float*)(ws + extoff);
    short* ext2 = (short*)(ws + extoff);

    k_prep<<<1, 256, 0, stream>>>(w1, w2, fcw, bn1g, bn2g,
                                  w1s, w2b, w2p, w2k, fcp, selb);
    k_conv1_mm2<<<MM2_BLOCKS, 256, 0, stream>>>(x, w1s, b1, selb, ext1, partial1);
    k_finalize1<<<16, 256, 0, stream>>>(partial1, MM2_BLOCKS, bn1g, bn1b, thr1, mode1);
    k_sign1<<<A1S_BLOCKS, 256, 0, stream>>>(ext1, thr1, mode1, a1b);
    k_conv2_fused<<<C2F_BLOCKS, 256, 0, stream>>>(a1b, w2p, w2k, selb, ext2, partial2);
    k_finalize2i<<<32, 256, 0, stream>>>(partial2, C2F_BLOCKS, b2, bn2g, bn2b, thr2, mode2);
    k_sign2<<<NPOOL2/256, 256, 0, stream>>>(ext2, b2, thr2, mode2, a2);
    k_fc<<<320, 256, 0, stream>>>(a2, fcp, fcb, out);
}